// Round 3
// baseline (461.959 us; speedup 1.0000x reference)
//
#include <hip/hip_runtime.h>

// Problem constants (from reference config)
#define BATCH 4
#define NCAM  6
#define DNUM  41
#define FHN   8
#define FWN   22
#define CCH   128
#define NXV   200
#define NYV   200
#define NXY   40000      // NXV*NYV
#define NPTS  173184     // BATCH*NCAM*DNUM*FHN*FWN
#define SBINS (BATCH * NXY)   // 160000 voxel bins
#define SPAD  160256          // 626 * 256 (scan padding)
#define SCAN_BLOCKS 626

struct Mats {
    float iR[9];    // inv(post_rots), fp32 LU (gesv-style)
    float comb[9];  // rots @ inv(intrins), fp32 no-FMA matmul
    float tr[3];    // trans
    float pt[3];    // post_trans
};

// fp32 3x3 inverse mimicking numpy's linalg.inv -> LAPACK sgesv:
// getf2 partial-pivot LU with reciprocal-scaled columns, then unit-lower
// forward solve + reciprocal-multiply backward solve vs identity. No FMA.
__device__ void inv3x3_f32_gesv(const float* __restrict__ Ain, float* __restrict__ inv) {
#pragma clang fp contract(off)
    float A[9];
    for (int k = 0; k < 9; ++k) A[k] = Ain[k];
    int piv[3];
    for (int j = 0; j < 3; ++j) {
        int p = j;
        float amax = fabsf(A[j * 3 + j]);
        for (int i = j + 1; i < 3; ++i) {
            float v = fabsf(A[i * 3 + j]);
            if (v > amax) { amax = v; p = i; }
        }
        piv[j] = p;
        if (p != j)
            for (int k = 0; k < 3; ++k) { float t = A[j*3+k]; A[j*3+k] = A[p*3+k]; A[p*3+k] = t; }
        float rd = 1.0f / A[j * 3 + j];
        for (int i = j + 1; i < 3; ++i) A[i * 3 + j] = A[i * 3 + j] * rd;
        for (int i = j + 1; i < 3; ++i)
            for (int k = j + 1; k < 3; ++k)
                A[i * 3 + k] = A[i * 3 + k] - A[i * 3 + j] * A[j * 3 + k];
    }
    float rdiag[3] = {1.0f / A[0], 1.0f / A[4], 1.0f / A[8]};
    for (int c = 0; c < 3; ++c) {
        float b[3] = {0.0f, 0.0f, 0.0f};
        b[c] = 1.0f;
        for (int j = 0; j < 3; ++j) { int p = piv[j]; if (p != j) { float t = b[j]; b[j] = b[p]; b[p] = t; } }
        for (int k = 0; k < 3; ++k)
            for (int i = k + 1; i < 3; ++i)
                b[i] = b[i] - A[i * 3 + k] * b[k];
        for (int k = 2; k >= 0; --k) {
            b[k] = b[k] * rdiag[k];
            for (int i = 0; i < k; ++i)
                b[i] = b[i] - A[i * 3 + k] * b[k];
        }
        inv[0 + c] = b[0];
        inv[3 + c] = b[1];
        inv[6 + c] = b[2];
    }
}

__global__ void prep_kernel(const float* __restrict__ rots,
                            const float* __restrict__ trans,
                            const float* __restrict__ intrins,
                            const float* __restrict__ post_rots,
                            const float* __restrict__ post_trans,
                            Mats* __restrict__ mats) {
    int i = threadIdx.x;
    if (i >= BATCH * NCAM) return;
    Mats m;
    inv3x3_f32_gesv(post_rots + i * 9, m.iR);
    float invK[9];
    inv3x3_f32_gesv(intrins + i * 9, invK);
    {
#pragma clang fp contract(off)
        for (int r = 0; r < 3; ++r)
            for (int c = 0; c < 3; ++c) {
                float s = rots[i * 9 + r * 3 + 0] * invK[0 * 3 + c];
                s = s + rots[i * 9 + r * 3 + 1] * invK[1 * 3 + c];
                s = s + rots[i * 9 + r * 3 + 2] * invK[2 * 3 + c];
                m.comb[r * 3 + c] = s;
            }
    }
    for (int k = 0; k < 3; ++k) {
        m.tr[k] = trans[i * 3 + k];
        m.pt[k] = post_trans[i * 3 + k];
    }
    mats[i] = m;
}

// Shared geometry: returns voxel flat index (b*NXY + gx*NYV + gy) or -1.
// BIT-EXACT copy of the version that passed verification — do not touch.
__device__ __forceinline__ int point_voxel(int p, const Mats* __restrict__ mats) {
#pragma clang fp contract(off)
    int w = p % FWN;
    int t = p / FWN;
    int h = t % FHN;
    t /= FHN;
    int d = t % DNUM;
    t /= DNUM;
    int n = t % NCAM;
    int b = t / NCAM;

    const Mats m = mats[b * NCAM + n];

    float u   = (float)((double)w * (351.0 / 21.0)); // linspace(0,351,22)
    float v   = (float)((double)h * (127.0 / 7.0));  // linspace(0,127,8)
    float dep = 4.0f + (float)d;                     // arange(4,45,1)

    float p0 = u - m.pt[0];
    float p1 = v - m.pt[1];
    float p2 = dep - m.pt[2];
    float q0 = m.iR[0] * p0; q0 = q0 + m.iR[1] * p1; q0 = q0 + m.iR[2] * p2;
    float q1 = m.iR[3] * p0; q1 = q1 + m.iR[4] * p1; q1 = q1 + m.iR[5] * p2;
    float q2 = m.iR[6] * p0; q2 = q2 + m.iR[7] * p1; q2 = q2 + m.iR[8] * p2;
    float r0 = q0 * q2;
    float r1 = q1 * q2;
    float e0 = m.comb[0] * r0; e0 = e0 + m.comb[1] * r1; e0 = e0 + m.comb[2] * q2; e0 = e0 + m.tr[0];
    float e1 = m.comb[3] * r0; e1 = e1 + m.comb[4] * r1; e1 = e1 + m.comb[5] * q2; e1 = e1 + m.tr[1];
    float e2 = m.comb[6] * r0; e2 = e2 + m.comb[7] * r1; e2 = e2 + m.comb[8] * q2; e2 = e2 + m.tr[2];

    float gxf = (e0 + 50.0f) / 0.5f;
    float gyf = (e1 + 50.0f) / 0.5f;
    float gzf = (e2 + 10.0f) / 20.0f;
    int gx = (int)gxf;
    int gy = (int)gyf;
    int gz = (int)gzf;
    if (gx < 0 || gx >= NXV || gy < 0 || gy >= NYV || gz < 0 || gz >= 1) return -1;
    return b * NXY + gx * NYV + gy;
}

// ---------------- CSR binning + gather path (no float atomics) ----------------

// Pass 1: one thread per point — geometry once (not 128x redundantly), store vid,
// count per bin with int atomics (62k ops, negligible).
__global__ __launch_bounds__(256) void vid_kernel(const Mats* __restrict__ mats,
                                                  int* __restrict__ vids,
                                                  int* __restrict__ counts) {
    int p = blockIdx.x * 256 + threadIdx.x;
    if (p >= NPTS) return;
    int vid = point_voxel(p, mats);
    vids[p] = vid;
    if (vid >= 0) atomicAdd(&counts[vid], 1);
}

// Pass 2a: per-256-chunk exclusive scan; chunk totals to blockSums.
__global__ __launch_bounds__(256) void scan_a(const int* __restrict__ counts,
                                              int* __restrict__ offsets,
                                              int* __restrict__ blockSums) {
    __shared__ int buf[2][256];
    int t = threadIdx.x;
    int g = blockIdx.x * 256 + t;       // grid covers SPAD exactly; counts zero-padded
    int v = counts[g];
    buf[0][t] = v;
    __syncthreads();
    int src = 0;
    for (int off = 1; off < 256; off <<= 1) {
        int val = buf[src][t];
        if (t >= off) val += buf[src][t - off];
        buf[src ^ 1][t] = val;
        __syncthreads();
        src ^= 1;
    }
    int incl = buf[src][t];
    offsets[g] = incl - v;              // exclusive within chunk
    if (t == 255) blockSums[blockIdx.x] = incl;
}

// Pass 2b: exclusive scan of the 626 chunk totals in one block.
__global__ __launch_bounds__(1024) void scan_b(int* __restrict__ blockSums) {
    __shared__ int buf[2][1024];
    int t = threadIdx.x;
    int v = (t < SCAN_BLOCKS) ? blockSums[t] : 0;
    buf[0][t] = v;
    __syncthreads();
    int src = 0;
    for (int off = 1; off < 1024; off <<= 1) {
        int val = buf[src][t];
        if (t >= off) val += buf[src][t - off];
        buf[src ^ 1][t] = val;
        __syncthreads();
        src ^= 1;
    }
    int incl = buf[src][t];
    if (t < SCAN_BLOCKS) blockSums[t] = incl - v;   // exclusive, in place
}

// Pass 2c: add chunk bases; also init mutable fill cursors.
__global__ __launch_bounds__(256) void scan_c(int* __restrict__ offsets,
                                              const int* __restrict__ blockSums,
                                              int* __restrict__ cursor) {
    int g = blockIdx.x * 256 + threadIdx.x;
    int v = offsets[g] + blockSums[blockIdx.x];
    offsets[g] = v;
    cursor[g] = v;
}

// Pass 3: scatter point ids into CSR slots (62k int atomics).
__global__ __launch_bounds__(256) void fill_kernel(const int* __restrict__ vids,
                                                   int* __restrict__ cursor,
                                                   int* __restrict__ plist) {
    int p = blockIdx.x * 256 + threadIdx.x;
    if (p >= NPTS) return;
    int vid = vids[p];
    if (vid >= 0) plist[atomicAdd(&cursor[vid], 1)] = p;
}

// Pass 4: gather. Block = 128 threads (one per channel), tile = 32 consecutive xy
// bins of one batch. Register-accumulate each bin's points (coalesced 512B feats
// reads), stage the 32x128 tile in LDS, write out[b][c][xy] transposed+coalesced.
// Writes EVERY output element exactly once -> no out memset, no vox, no transpose.
__global__ __launch_bounds__(128) void gather_kernel(const float* __restrict__ feats,
                                                     const int* __restrict__ plist,
                                                     const int* __restrict__ offsets,
                                                     const int* __restrict__ counts,
                                                     float* __restrict__ out) {
    __shared__ float acc[32][129];      // +1 pad: conflict-free on both phases
    __shared__ int s_beg[32], s_cnt[32];
    int c = threadIdx.x;
    int xy0 = blockIdx.x * 32;
    int b = blockIdx.y;
    int bin0 = b * NXY + xy0;
    if (c < 32) {
        s_beg[c] = offsets[bin0 + c];
        s_cnt[c] = counts[bin0 + c];
    }
    __syncthreads();
    for (int j = 0; j < 32; ++j) {
        int beg = s_beg[j];
        int cnt = s_cnt[j];
        float s = 0.0f;
        for (int k = 0; k < cnt; ++k) {
            int p = plist[beg + k];
            s += feats[(size_t)p * CCH + c];
        }
        acc[j][c] = s;                  // banks (j+c)%32: 2 lanes/bank — free
    }
    __syncthreads();
    int tx = c & 31, tg = c >> 5;
    float* dst = out + (size_t)b * CCH * NXY;
#pragma unroll
    for (int cc = 0; cc < 32; ++cc) {
        int ch = cc * 4 + tg;
        // wave = two 128B contiguous segments (ch, ch+1) — coalesced
        dst[(size_t)ch * NXY + xy0 + tx] = acc[tx][ch];
    }
}

// ---------------- Fallback (tiny workspace): direct atomic scatter ----------------
__global__ __launch_bounds__(128) void scatter_direct_kernel(const float* __restrict__ feats,
                                                             const Mats* __restrict__ mats,
                                                             float* __restrict__ out) {
    int p = blockIdx.x;
    int vid = point_voxel(p, mats);
    if (vid < 0) return;
    int b  = vid / NXY;
    int xy = vid % NXY;
    int c = threadIdx.x;
    float f = feats[(size_t)p * CCH + c];
    atomicAdd(out + (size_t)(b * CCH + c) * NXY + xy, f);
}

extern "C" void kernel_launch(void* const* d_in, const int* in_sizes, int n_in,
                              void* d_out, int out_size, void* d_ws, size_t ws_size,
                              hipStream_t stream) {
    const float* cam_feats  = (const float*)d_in[0];
    const float* rots       = (const float*)d_in[1];
    const float* trans      = (const float*)d_in[2];
    const float* intrins    = (const float*)d_in[3];
    const float* post_rots  = (const float*)d_in[4];
    const float* post_trans = (const float*)d_in[5];
    float* out = (float*)d_out;
    Mats* mats = (Mats*)d_ws;

    prep_kernel<<<1, 64, 0, stream>>>(rots, trans, intrins, post_rots, post_trans, mats);

    // Workspace layout (all 256B-aligned; total ~3.2 MB)
    const size_t OFF_VIDS    = 4096;                          // NPTS ints
    const size_t OFF_PLIST   = OFF_VIDS   + (size_t)NPTS * 4; // NPTS ints
    const size_t OFF_COUNTS  = OFF_PLIST  + (size_t)NPTS * 4; // SPAD ints
    const size_t OFF_OFFSETS = OFF_COUNTS + (size_t)SPAD * 4; // SPAD ints
    const size_t OFF_CURSOR  = OFF_OFFSETS+ (size_t)SPAD * 4; // SPAD ints
    const size_t OFF_BSUMS   = OFF_CURSOR + (size_t)SPAD * 4; // SCAN_BLOCKS ints
    const size_t WS_NEEDED   = OFF_BSUMS + (size_t)SCAN_BLOCKS * 4;

    if (ws_size >= WS_NEEDED) {
        int* vids    = (int*)((char*)d_ws + OFF_VIDS);
        int* plist   = (int*)((char*)d_ws + OFF_PLIST);
        int* counts  = (int*)((char*)d_ws + OFF_COUNTS);
        int* offsets = (int*)((char*)d_ws + OFF_OFFSETS);
        int* cursor  = (int*)((char*)d_ws + OFF_CURSOR);
        int* bsums   = (int*)((char*)d_ws + OFF_BSUMS);

        hipMemsetAsync(counts, 0, (size_t)SPAD * 4, stream);

        const int ptBlocks = (NPTS + 255) / 256;  // 677
        vid_kernel<<<ptBlocks, 256, 0, stream>>>(mats, vids, counts);
        scan_a<<<SCAN_BLOCKS, 256, 0, stream>>>(counts, offsets, bsums);
        scan_b<<<1, 1024, 0, stream>>>(bsums);
        scan_c<<<SCAN_BLOCKS, 256, 0, stream>>>(offsets, bsums, cursor);
        fill_kernel<<<ptBlocks, 256, 0, stream>>>(vids, cursor, plist);

        dim3 ggrid(NXY / 32, BATCH);              // (1250, 4)
        gather_kernel<<<ggrid, 128, 0, stream>>>(cam_feats, plist, offsets, counts, out);
    } else {
        hipMemsetAsync(d_out, 0, (size_t)out_size * sizeof(float), stream);
        scatter_direct_kernel<<<NPTS, CCH, 0, stream>>>(cam_feats, mats, out);
    }
}

// Round 5
// 277.779 us; speedup vs baseline: 1.6630x; 1.6630x over previous
//
#include <hip/hip_runtime.h>

// Problem constants (from reference config)
#define BATCH 4
#define NCAM  6
#define DNUM  41
#define FHN   8
#define FWN   22
#define CCH   128
#define NXV   200
#define NYV   200
#define NXY   40000      // NXV*NYV
#define NPTS  173184     // BATCH*NCAM*DNUM*FHN*FWN
#define SBINS (BATCH * NXY)   // 160000 voxel bins
#define CAP   64         // bucket capacity per bin (avg occupancy ~0.4)
#define OVF_MAX 8192     // overflow side-list capacity

struct Mats {
    float iR[9];    // inv(post_rots), fp32 LU (gesv-style)
    float comb[9];  // rots @ inv(intrins), fp32 no-FMA matmul
    float tr[3];    // trans
    float pt[3];    // post_trans
};

// fp32 3x3 inverse mimicking numpy's linalg.inv -> LAPACK sgesv:
// getf2 partial-pivot LU with reciprocal-scaled columns, then unit-lower
// forward solve + reciprocal-multiply backward solve vs identity. No FMA.
__device__ void inv3x3_f32_gesv(const float* __restrict__ Ain, float* __restrict__ inv) {
#pragma clang fp contract(off)
    float A[9];
    for (int k = 0; k < 9; ++k) A[k] = Ain[k];
    int piv[3];
    for (int j = 0; j < 3; ++j) {
        int p = j;
        float amax = fabsf(A[j * 3 + j]);
        for (int i = j + 1; i < 3; ++i) {
            float v = fabsf(A[i * 3 + j]);
            if (v > amax) { amax = v; p = i; }
        }
        piv[j] = p;
        if (p != j)
            for (int k = 0; k < 3; ++k) { float t = A[j*3+k]; A[j*3+k] = A[p*3+k]; A[p*3+k] = t; }
        float rd = 1.0f / A[j * 3 + j];
        for (int i = j + 1; i < 3; ++i) A[i * 3 + j] = A[i * 3 + j] * rd;
        for (int i = j + 1; i < 3; ++i)
            for (int k = j + 1; k < 3; ++k)
                A[i * 3 + k] = A[i * 3 + k] - A[i * 3 + j] * A[j * 3 + k];
    }
    float rdiag[3] = {1.0f / A[0], 1.0f / A[4], 1.0f / A[8]};
    for (int c = 0; c < 3; ++c) {
        float b[3] = {0.0f, 0.0f, 0.0f};
        b[c] = 1.0f;
        for (int j = 0; j < 3; ++j) { int p = piv[j]; if (p != j) { float t = b[j]; b[j] = b[p]; b[p] = t; } }
        for (int k = 0; k < 3; ++k)
            for (int i = k + 1; i < 3; ++i)
                b[i] = b[i] - A[i * 3 + k] * b[k];
        for (int k = 2; k >= 0; --k) {
            b[k] = b[k] * rdiag[k];
            for (int i = 0; i < k; ++i)
                b[i] = b[i] - A[i * 3 + k] * b[k];
        }
        inv[0 + c] = b[0];
        inv[3 + c] = b[1];
        inv[6 + c] = b[2];
    }
}

// Compute one camera's Mats (identical fp sequence to the old prep_kernel).
__device__ void compute_mats(int i,
                             const float* __restrict__ rots,
                             const float* __restrict__ trans,
                             const float* __restrict__ intrins,
                             const float* __restrict__ post_rots,
                             const float* __restrict__ post_trans,
                             Mats* __restrict__ m) {
    inv3x3_f32_gesv(post_rots + i * 9, m->iR);
    float invK[9];
    inv3x3_f32_gesv(intrins + i * 9, invK);
    {
#pragma clang fp contract(off)
        for (int r = 0; r < 3; ++r)
            for (int c = 0; c < 3; ++c) {
                float s = rots[i * 9 + r * 3 + 0] * invK[0 * 3 + c];
                s = s + rots[i * 9 + r * 3 + 1] * invK[1 * 3 + c];
                s = s + rots[i * 9 + r * 3 + 2] * invK[2 * 3 + c];
                m->comb[r * 3 + c] = s;
            }
    }
    for (int k = 0; k < 3; ++k) {
        m->tr[k] = trans[i * 3 + k];
        m->pt[k] = post_trans[i * 3 + k];
    }
}

__global__ void prep_kernel(const float* __restrict__ rots,
                            const float* __restrict__ trans,
                            const float* __restrict__ intrins,
                            const float* __restrict__ post_rots,
                            const float* __restrict__ post_trans,
                            Mats* __restrict__ mats) {
    int i = threadIdx.x;
    if (i >= BATCH * NCAM) return;
    Mats m;
    compute_mats(i, rots, trans, intrins, post_rots, post_trans, &m);
    mats[i] = m;
}

// Shared geometry: returns voxel flat index (b*NXY + gx*NYV + gy) or -1.
// BIT-EXACT fp sequence of the verified version — do not touch.
__device__ __forceinline__ int point_voxel(int p, const Mats* __restrict__ mats) {
#pragma clang fp contract(off)
    int w = p % FWN;
    int t = p / FWN;
    int h = t % FHN;
    t /= FHN;
    int d = t % DNUM;
    t /= DNUM;
    int n = t % NCAM;
    int b = t / NCAM;

    const Mats m = mats[b * NCAM + n];

    float u   = (float)((double)w * (351.0 / 21.0)); // linspace(0,351,22)
    float v   = (float)((double)h * (127.0 / 7.0));  // linspace(0,127,8)
    float dep = 4.0f + (float)d;                     // arange(4,45,1)

    float p0 = u - m.pt[0];
    float p1 = v - m.pt[1];
    float p2 = dep - m.pt[2];
    float q0 = m.iR[0] * p0; q0 = q0 + m.iR[1] * p1; q0 = q0 + m.iR[2] * p2;
    float q1 = m.iR[3] * p0; q1 = q1 + m.iR[4] * p1; q1 = q1 + m.iR[5] * p2;
    float q2 = m.iR[6] * p0; q2 = q2 + m.iR[7] * p1; q2 = q2 + m.iR[8] * p2;
    float r0 = q0 * q2;
    float r1 = q1 * q2;
    float e0 = m.comb[0] * r0; e0 = e0 + m.comb[1] * r1; e0 = e0 + m.comb[2] * q2; e0 = e0 + m.tr[0];
    float e1 = m.comb[3] * r0; e1 = e1 + m.comb[4] * r1; e1 = e1 + m.comb[5] * q2; e1 = e1 + m.tr[1];
    float e2 = m.comb[6] * r0; e2 = e2 + m.comb[7] * r1; e2 = e2 + m.comb[8] * q2; e2 = e2 + m.tr[2];

    float gxf = (e0 + 50.0f) / 0.5f;
    float gyf = (e1 + 50.0f) / 0.5f;
    float gzf = (e2 + 10.0f) / 20.0f;
    int gx = (int)gxf;
    int gy = (int)gyf;
    int gz = (int)gzf;
    if (gx < 0 || gx >= NXV || gy < 0 || gy >= NYV || gz < 0 || gz >= 1) return -1;
    return b * NXY + gx * NYV + gy;
}

// ---------------- Bucketed binning + parallel gather (3 launches) ----------------

// One kernel: per-block Mats in LDS (replaces prep launch), then one thread per
// point: geometry -> fixed-capacity bucket via per-bin atomic cursor.
// Overflow (>CAP points in a bin — practically never) goes to a side list.
__global__ __launch_bounds__(256) void bucket_kernel(const float* __restrict__ rots,
                                                     const float* __restrict__ trans,
                                                     const float* __restrict__ intrins,
                                                     const float* __restrict__ post_rots,
                                                     const float* __restrict__ post_trans,
                                                     int* __restrict__ counts,
                                                     int* __restrict__ bucket,
                                                     int* __restrict__ ovfcnt,
                                                     int2* __restrict__ ovf) {
    __shared__ Mats smats[BATCH * NCAM];
    int t = threadIdx.x;
    if (t < BATCH * NCAM) {
        Mats m;
        compute_mats(t, rots, trans, intrins, post_rots, post_trans, &m);
        smats[t] = m;
    }
    __syncthreads();
    int p = blockIdx.x * 256 + t;
    if (p >= NPTS) return;
    int vid = point_voxel(p, smats);
    if (vid < 0) return;
    int slot = atomicAdd(&counts[vid], 1);
    if (slot < CAP) {
        bucket[(size_t)vid * CAP + slot] = p;
    } else {
        int o = atomicAdd(ovfcnt, 1);
        if (o < OVF_MAX) ovf[o] = make_int2(vid, p);
    }
}

// Gather v2: block = 256 threads = (32 bins x 8 channel-groups). Each thread
// accumulates 16 channels (4x float4, ILP=4) of ONE bin — critical path is
// max-cnt-per-bin, not sum over 32 bins. Empty tiles (common: frustum covers a
// minority of the BEV grid) short-circuit to a coalesced zero-write.
// Output transposed through padded LDS tile, written exactly once (no memset).
__global__ __launch_bounds__(256) void gather2_kernel(const float* __restrict__ feats,
                                                      const int* __restrict__ counts,
                                                      const int* __restrict__ bucket,
                                                      const int* __restrict__ ovfcnt,
                                                      const int2* __restrict__ ovf,
                                                      float* __restrict__ out) {
    __shared__ float acc[32][129];      // scalar r/w: 2-lanes/bank both phases (free)
    int t = threadIdx.x;
    int j = t >> 3;                     // bin within tile   [0,32)
    int g = t & 7;                      // channel group     [0,8) x 16 ch
    int xy0 = blockIdx.x * 32;
    int b = blockIdx.y;
    int bin = b * NXY + xy0 + j;

    int cntRaw = counts[bin];
    int cnt = cntRaw < CAP ? cntRaw : CAP;

    float4 a0 = {0.f,0.f,0.f,0.f}, a1 = a0, a2 = a0, a3 = a0;
    const int* bk = bucket + (size_t)bin * CAP;
    const float* fg = feats + g * 16;
    for (int k = 0; k < cnt; ++k) {
        int p = bk[k];
        const float4* f4 = (const float4*)(fg + (size_t)p * CCH);
        float4 v0 = f4[0], v1 = f4[1], v2 = f4[2], v3 = f4[3];
        a0.x += v0.x; a0.y += v0.y; a0.z += v0.z; a0.w += v0.w;
        a1.x += v1.x; a1.y += v1.y; a1.z += v1.z; a1.w += v1.w;
        a2.x += v2.x; a2.y += v2.y; a2.z += v2.z; a2.w += v2.w;
        a3.x += v3.x; a3.y += v3.y; a3.z += v3.z; a3.w += v3.w;
    }
    // Overflow side list (normally empty: one broadcast load, loop skipped).
    int novf = ovfcnt[0];
    if (novf > 0) {
        if (novf > OVF_MAX) novf = OVF_MAX;
        for (int e = 0; e < novf; ++e) {
            int2 vp = ovf[e];
            if (vp.x == bin) {
                const float4* f4 = (const float4*)(fg + (size_t)vp.y * CCH);
                float4 v0 = f4[0], v1 = f4[1], v2 = f4[2], v3 = f4[3];
                a0.x += v0.x; a0.y += v0.y; a0.z += v0.z; a0.w += v0.w;
                a1.x += v1.x; a1.y += v1.y; a1.z += v1.z; a1.w += v1.w;
                a2.x += v2.x; a2.y += v2.y; a2.z += v2.z; a2.w += v2.w;
                a3.x += v3.x; a3.y += v3.y; a3.z += v3.z; a3.w += v3.w;
            }
        }
    }

    int nz = __syncthreads_count(cnt != 0);
    int tx = t & 31, tg = t >> 5;
    float* dst = out + (size_t)b * CCH * NXY + xy0 + tx;
    if (nz == 0) {
        // whole tile empty: coalesced zero-fill, skip LDS entirely
#pragma unroll
        for (int cc = 0; cc < 16; ++cc)
            dst[(size_t)(cc * 8 + tg) * NXY] = 0.0f;
        return;
    }

    float* row = &acc[j][g * 16];
    row[0]  = a0.x; row[1]  = a0.y; row[2]  = a0.z; row[3]  = a0.w;
    row[4]  = a1.x; row[5]  = a1.y; row[6]  = a1.z; row[7]  = a1.w;
    row[8]  = a2.x; row[9]  = a2.y; row[10] = a2.z; row[11] = a2.w;
    row[12] = a3.x; row[13] = a3.y; row[14] = a3.z; row[15] = a3.w;
    __syncthreads();

    // transposed write: wave = 2 chans x 128B contiguous segments — coalesced
#pragma unroll
    for (int cc = 0; cc < 16; ++cc) {
        int ch = cc * 8 + tg;
        dst[(size_t)ch * NXY] = acc[tx][ch];
    }
}

// ---------------- Fallback (tiny workspace): direct atomic scatter ----------------
__global__ __launch_bounds__(128) void scatter_direct_kernel(const float* __restrict__ feats,
                                                             const Mats* __restrict__ mats,
                                                             float* __restrict__ out) {
    int p = blockIdx.x;
    int vid = point_voxel(p, mats);
    if (vid < 0) return;
    int b  = vid / NXY;
    int xy = vid % NXY;
    int c = threadIdx.x;
    float f = feats[(size_t)p * CCH + c];
    atomicAdd(out + (size_t)(b * CCH + c) * NXY + xy, f);
}

extern "C" void kernel_launch(void* const* d_in, const int* in_sizes, int n_in,
                              void* d_out, int out_size, void* d_ws, size_t ws_size,
                              hipStream_t stream) {
    const float* cam_feats  = (const float*)d_in[0];
    const float* rots       = (const float*)d_in[1];
    const float* trans      = (const float*)d_in[2];
    const float* intrins    = (const float*)d_in[3];
    const float* post_rots  = (const float*)d_in[4];
    const float* post_trans = (const float*)d_in[5];
    float* out = (float*)d_out;

    // Workspace layout (256B-aligned; ~41.7 MB total)
    const size_t OFF_COUNTS = 4096;                             // SBINS ints
    const size_t OFF_OVFCNT = OFF_COUNTS + (size_t)SBINS * 4;   // 1 int (in the memset span)
    const size_t OFF_OVF    = OFF_OVFCNT + 256;                 // OVF_MAX int2
    const size_t OFF_BUCKET = OFF_OVF + (size_t)OVF_MAX * 8;    // SBINS*CAP ints
    const size_t WS_NEEDED  = OFF_BUCKET + (size_t)SBINS * CAP * 4;

    if (ws_size >= WS_NEEDED) {
        int*  counts = (int*)((char*)d_ws + OFF_COUNTS);
        int*  ovfcnt = (int*)((char*)d_ws + OFF_OVFCNT);
        int2* ovf    = (int2*)((char*)d_ws + OFF_OVF);
        int*  bucket = (int*)((char*)d_ws + OFF_BUCKET);

        // one memset covers counts + ovfcnt
        hipMemsetAsync(counts, 0, (size_t)SBINS * 4 + 256, stream);

        const int ptBlocks = (NPTS + 255) / 256;  // 677
        bucket_kernel<<<ptBlocks, 256, 0, stream>>>(rots, trans, intrins, post_rots,
                                                    post_trans, counts, bucket, ovfcnt, ovf);

        dim3 ggrid(NXY / 32, BATCH);              // (1250, 4)
        gather2_kernel<<<ggrid, 256, 0, stream>>>(cam_feats, counts, bucket, ovfcnt, ovf, out);
    } else {
        Mats* mats = (Mats*)d_ws;
        prep_kernel<<<1, 64, 0, stream>>>(rots, trans, intrins, post_rots, post_trans, mats);
        hipMemsetAsync(d_out, 0, (size_t)out_size * sizeof(float), stream);
        scatter_direct_kernel<<<NPTS, CCH, 0, stream>>>(cam_feats, mats, out);
    }
}

// Round 6
// 229.227 us; speedup vs baseline: 2.0153x; 1.2118x over previous
//
#include <hip/hip_runtime.h>

// Problem constants (from reference config)
#define BATCH 4
#define NCAM  6
#define DNUM  41
#define FHN   8
#define FWN   22
#define CCH   128
#define NXV   200
#define NYV   200
#define NXY   40000      // NXV*NYV
#define NPTS  173184     // BATCH*NCAM*DNUM*FHN*FWN
#define SBINS (BATCH * NXY)   // 160000 voxel bins
#define CAP   64         // bucket capacity per bin (avg occupancy ~0.4)
#define OVF_MAX 8192     // overflow side-list capacity

struct Mats {
    float iR[9];    // inv(post_rots), fp32 LU (gesv-style)
    float comb[9];  // rots @ inv(intrins), fp32 no-FMA matmul
    float tr[3];    // trans
    float pt[3];    // post_trans
};

// fp32 3x3 inverse mimicking numpy's linalg.inv -> LAPACK sgesv:
// getf2 partial-pivot LU with reciprocal-scaled columns, then unit-lower
// forward solve + reciprocal-multiply backward solve vs identity. No FMA.
// NOTE: runtime-indexed arrays (pivot swaps) spill to scratch — this function
// must only ever run in ONE tiny one-shot kernel (prep), never per-block.
__device__ void inv3x3_f32_gesv(const float* __restrict__ Ain, float* __restrict__ inv) {
#pragma clang fp contract(off)
    float A[9];
    for (int k = 0; k < 9; ++k) A[k] = Ain[k];
    int piv[3];
    for (int j = 0; j < 3; ++j) {
        int p = j;
        float amax = fabsf(A[j * 3 + j]);
        for (int i = j + 1; i < 3; ++i) {
            float v = fabsf(A[i * 3 + j]);
            if (v > amax) { amax = v; p = i; }
        }
        piv[j] = p;
        if (p != j)
            for (int k = 0; k < 3; ++k) { float t = A[j*3+k]; A[j*3+k] = A[p*3+k]; A[p*3+k] = t; }
        float rd = 1.0f / A[j * 3 + j];
        for (int i = j + 1; i < 3; ++i) A[i * 3 + j] = A[i * 3 + j] * rd;
        for (int i = j + 1; i < 3; ++i)
            for (int k = j + 1; k < 3; ++k)
                A[i * 3 + k] = A[i * 3 + k] - A[i * 3 + j] * A[j * 3 + k];
    }
    float rdiag[3] = {1.0f / A[0], 1.0f / A[4], 1.0f / A[8]};
    for (int c = 0; c < 3; ++c) {
        float b[3] = {0.0f, 0.0f, 0.0f};
        b[c] = 1.0f;
        for (int j = 0; j < 3; ++j) { int p = piv[j]; if (p != j) { float t = b[j]; b[j] = b[p]; b[p] = t; } }
        for (int k = 0; k < 3; ++k)
            for (int i = k + 1; i < 3; ++i)
                b[i] = b[i] - A[i * 3 + k] * b[k];
        for (int k = 2; k >= 0; --k) {
            b[k] = b[k] * rdiag[k];
            for (int i = 0; i < k; ++i)
                b[i] = b[i] - A[i * 3 + k] * b[k];
        }
        inv[0 + c] = b[0];
        inv[3 + c] = b[1];
        inv[6 + c] = b[2];
    }
}

__global__ void prep_kernel(const float* __restrict__ rots,
                            const float* __restrict__ trans,
                            const float* __restrict__ intrins,
                            const float* __restrict__ post_rots,
                            const float* __restrict__ post_trans,
                            Mats* __restrict__ mats) {
    int i = threadIdx.x;
    if (i >= BATCH * NCAM) return;
    Mats m;
    inv3x3_f32_gesv(post_rots + i * 9, m.iR);
    float invK[9];
    inv3x3_f32_gesv(intrins + i * 9, invK);
    {
#pragma clang fp contract(off)
        for (int r = 0; r < 3; ++r)
            for (int c = 0; c < 3; ++c) {
                float s = rots[i * 9 + r * 3 + 0] * invK[0 * 3 + c];
                s = s + rots[i * 9 + r * 3 + 1] * invK[1 * 3 + c];
                s = s + rots[i * 9 + r * 3 + 2] * invK[2 * 3 + c];
                m.comb[r * 3 + c] = s;
            }
    }
    for (int k = 0; k < 3; ++k) {
        m.tr[k] = trans[i * 3 + k];
        m.pt[k] = post_trans[i * 3 + k];
    }
    mats[i] = m;
}

// Shared geometry: returns voxel flat index (b*NXY + gx*NYV + gy) or -1.
// BIT-EXACT fp sequence of the verified version — do not touch.
__device__ __forceinline__ int point_voxel(int p, const Mats* __restrict__ mats) {
#pragma clang fp contract(off)
    int w = p % FWN;
    int t = p / FWN;
    int h = t % FHN;
    t /= FHN;
    int d = t % DNUM;
    t /= DNUM;
    int n = t % NCAM;
    int b = t / NCAM;

    const Mats m = mats[b * NCAM + n];

    float u   = (float)((double)w * (351.0 / 21.0)); // linspace(0,351,22)
    float v   = (float)((double)h * (127.0 / 7.0));  // linspace(0,127,8)
    float dep = 4.0f + (float)d;                     // arange(4,45,1)

    float p0 = u - m.pt[0];
    float p1 = v - m.pt[1];
    float p2 = dep - m.pt[2];
    float q0 = m.iR[0] * p0; q0 = q0 + m.iR[1] * p1; q0 = q0 + m.iR[2] * p2;
    float q1 = m.iR[3] * p0; q1 = q1 + m.iR[4] * p1; q1 = q1 + m.iR[5] * p2;
    float q2 = m.iR[6] * p0; q2 = q2 + m.iR[7] * p1; q2 = q2 + m.iR[8] * p2;
    float r0 = q0 * q2;
    float r1 = q1 * q2;
    float e0 = m.comb[0] * r0; e0 = e0 + m.comb[1] * r1; e0 = e0 + m.comb[2] * q2; e0 = e0 + m.tr[0];
    float e1 = m.comb[3] * r0; e1 = e1 + m.comb[4] * r1; e1 = e1 + m.comb[5] * q2; e1 = e1 + m.tr[1];
    float e2 = m.comb[6] * r0; e2 = e2 + m.comb[7] * r1; e2 = e2 + m.comb[8] * q2; e2 = e2 + m.tr[2];

    float gxf = (e0 + 50.0f) / 0.5f;
    float gyf = (e1 + 50.0f) / 0.5f;
    float gzf = (e2 + 10.0f) / 20.0f;
    int gx = (int)gxf;
    int gy = (int)gyf;
    int gz = (int)gzf;
    if (gx < 0 || gx >= NXV || gy < 0 || gy >= NYV || gz < 0 || gz >= 1) return -1;
    return b * NXY + gx * NYV + gy;
}

// ---------------- Bucketed binning + parallel gather ----------------

// One thread per point: geometry (mats from global — broadcast, L1-cached) ->
// fixed-capacity bucket via per-bin atomic cursor. Overflow -> side list.
__global__ __launch_bounds__(256) void bucket_kernel(const Mats* __restrict__ mats,
                                                     int* __restrict__ counts,
                                                     int* __restrict__ bucket,
                                                     int* __restrict__ ovfcnt,
                                                     int2* __restrict__ ovf) {
    int p = blockIdx.x * 256 + threadIdx.x;
    if (p >= NPTS) return;
    int vid = point_voxel(p, mats);
    if (vid < 0) return;
    int slot = atomicAdd(&counts[vid], 1);
    if (slot < CAP) {
        bucket[(size_t)vid * CAP + slot] = p;
    } else {
        int o = atomicAdd(ovfcnt, 1);
        if (o < OVF_MAX) ovf[o] = make_int2(vid, p);
    }
}

// Gather v3: block = 256 threads = (32 bins x 8 channel-groups); each thread owns
// 16 channels of ONE bin. Bucket indices prefetched as int4; feats loads issued
// in batches of 4 points x 4 float4 = 16 independent loads in flight (ILP), then
// accumulated IN ORDER (k sequential — same summation order as v2).
// Empty tiles short-circuit to a coalesced zero-write. Output written exactly
// once, transposed through padded LDS tile (no out memset needed).
__global__ __launch_bounds__(256) void gather3_kernel(const float* __restrict__ feats,
                                                      const int* __restrict__ counts,
                                                      const int* __restrict__ bucket,
                                                      const int* __restrict__ ovfcnt,
                                                      const int2* __restrict__ ovf,
                                                      float* __restrict__ out) {
    __shared__ float acc[32][129];      // scalar r/w: 2-lanes/bank both phases (free)
    int t = threadIdx.x;
    int j = t >> 3;                     // bin within tile   [0,32)
    int g = t & 7;                      // channel group     [0,8) x 16 ch
    int xy0 = blockIdx.x * 32;
    int b = blockIdx.y;
    int bin = b * NXY + xy0 + j;

    int cntRaw = counts[bin];
    int cnt = cntRaw < CAP ? cntRaw : CAP;

    float4 a0 = {0.f,0.f,0.f,0.f}, a1 = a0, a2 = a0, a3 = a0;
    const int* bk = bucket + (size_t)bin * CAP;   // 256B-aligned row
    const float* fg = feats + g * 16;

    int k = 0;
    // batched path: 4 points per step, 16 loads in flight before any add
    for (; k + 4 <= cnt; k += 4) {
        int4 pp = *(const int4*)(bk + k);         // aligned: k%4==0, row 256B-aligned
        const float4* f0 = (const float4*)(fg + (size_t)pp.x * CCH);
        const float4* f1 = (const float4*)(fg + (size_t)pp.y * CCH);
        const float4* f2 = (const float4*)(fg + (size_t)pp.z * CCH);
        const float4* f3 = (const float4*)(fg + (size_t)pp.w * CCH);
        float4 v00 = f0[0], v01 = f0[1], v02 = f0[2], v03 = f0[3];
        float4 v10 = f1[0], v11 = f1[1], v12 = f1[2], v13 = f1[3];
        float4 v20 = f2[0], v21 = f2[1], v22 = f2[2], v23 = f2[3];
        float4 v30 = f3[0], v31 = f3[1], v32 = f3[2], v33 = f3[3];
        // accumulate in k order (matches v2 summation order)
        a0.x += v00.x; a0.y += v00.y; a0.z += v00.z; a0.w += v00.w;
        a1.x += v01.x; a1.y += v01.y; a1.z += v01.z; a1.w += v01.w;
        a2.x += v02.x; a2.y += v02.y; a2.z += v02.z; a2.w += v02.w;
        a3.x += v03.x; a3.y += v03.y; a3.z += v03.z; a3.w += v03.w;
        a0.x += v10.x; a0.y += v10.y; a0.z += v10.z; a0.w += v10.w;
        a1.x += v11.x; a1.y += v11.y; a1.z += v11.z; a1.w += v11.w;
        a2.x += v12.x; a2.y += v12.y; a2.z += v12.z; a2.w += v12.w;
        a3.x += v13.x; a3.y += v13.y; a3.z += v13.z; a3.w += v13.w;
        a0.x += v20.x; a0.y += v20.y; a0.z += v20.z; a0.w += v20.w;
        a1.x += v21.x; a1.y += v21.y; a1.z += v21.z; a1.w += v21.w;
        a2.x += v22.x; a2.y += v22.y; a2.z += v22.z; a2.w += v22.w;
        a3.x += v23.x; a3.y += v23.y; a3.z += v23.z; a3.w += v23.w;
        a0.x += v30.x; a0.y += v30.y; a0.z += v30.z; a0.w += v30.w;
        a1.x += v31.x; a1.y += v31.y; a1.z += v31.z; a1.w += v31.w;
        a2.x += v32.x; a2.y += v32.y; a2.z += v32.z; a2.w += v32.w;
        a3.x += v33.x; a3.y += v33.y; a3.z += v33.z; a3.w += v33.w;
    }
    for (; k < cnt; ++k) {
        int p = bk[k];
        const float4* f4 = (const float4*)(fg + (size_t)p * CCH);
        float4 v0 = f4[0], v1 = f4[1], v2 = f4[2], v3 = f4[3];
        a0.x += v0.x; a0.y += v0.y; a0.z += v0.z; a0.w += v0.w;
        a1.x += v1.x; a1.y += v1.y; a1.z += v1.z; a1.w += v1.w;
        a2.x += v2.x; a2.y += v2.y; a2.z += v2.z; a2.w += v2.w;
        a3.x += v3.x; a3.y += v3.y; a3.z += v3.z; a3.w += v3.w;
    }

    // Overflow side list (normally empty: one broadcast load, loop skipped).
    int novf = ovfcnt[0];
    if (novf > 0) {
        if (novf > OVF_MAX) novf = OVF_MAX;
        for (int e = 0; e < novf; ++e) {
            int2 vp = ovf[e];
            if (vp.x == bin) {
                const float4* f4 = (const float4*)(fg + (size_t)vp.y * CCH);
                float4 v0 = f4[0], v1 = f4[1], v2 = f4[2], v3 = f4[3];
                a0.x += v0.x; a0.y += v0.y; a0.z += v0.z; a0.w += v0.w;
                a1.x += v1.x; a1.y += v1.y; a1.z += v1.z; a1.w += v1.w;
                a2.x += v2.x; a2.y += v2.y; a2.z += v2.z; a2.w += v2.w;
                a3.x += v3.x; a3.y += v3.y; a3.z += v3.z; a3.w += v3.w;
            }
        }
    }

    int nz = __syncthreads_count(cnt != 0);
    int tx = t & 31, tg = t >> 5;
    float* dst = out + (size_t)b * CCH * NXY + xy0 + tx;
    if (nz == 0) {
        // whole tile empty: coalesced zero-fill, skip LDS entirely
#pragma unroll
        for (int cc = 0; cc < 16; ++cc)
            dst[(size_t)(cc * 8 + tg) * NXY] = 0.0f;
        return;
    }

    float* row = &acc[j][g * 16];
    row[0]  = a0.x; row[1]  = a0.y; row[2]  = a0.z; row[3]  = a0.w;
    row[4]  = a1.x; row[5]  = a1.y; row[6]  = a1.z; row[7]  = a1.w;
    row[8]  = a2.x; row[9]  = a2.y; row[10] = a2.z; row[11] = a2.w;
    row[12] = a3.x; row[13] = a3.y; row[14] = a3.z; row[15] = a3.w;
    __syncthreads();

    // transposed write: wave = 2 chans x 128B contiguous segments — coalesced
#pragma unroll
    for (int cc = 0; cc < 16; ++cc) {
        int ch = cc * 8 + tg;
        dst[(size_t)ch * NXY] = acc[tx][ch];
    }
}

// ---------------- Fallback (tiny workspace): direct atomic scatter ----------------
__global__ __launch_bounds__(128) void scatter_direct_kernel(const float* __restrict__ feats,
                                                             const Mats* __restrict__ mats,
                                                             float* __restrict__ out) {
    int p = blockIdx.x;
    int vid = point_voxel(p, mats);
    if (vid < 0) return;
    int b  = vid / NXY;
    int xy = vid % NXY;
    int c = threadIdx.x;
    float f = feats[(size_t)p * CCH + c];
    atomicAdd(out + (size_t)(b * CCH + c) * NXY + xy, f);
}

extern "C" void kernel_launch(void* const* d_in, const int* in_sizes, int n_in,
                              void* d_out, int out_size, void* d_ws, size_t ws_size,
                              hipStream_t stream) {
    const float* cam_feats  = (const float*)d_in[0];
    const float* rots       = (const float*)d_in[1];
    const float* trans      = (const float*)d_in[2];
    const float* intrins    = (const float*)d_in[3];
    const float* post_rots  = (const float*)d_in[4];
    const float* post_trans = (const float*)d_in[5];
    float* out = (float*)d_out;
    Mats* mats = (Mats*)d_ws;                                   // 24*96B at offset 0

    // Workspace layout (256B-aligned; ~41.7 MB total)
    const size_t OFF_COUNTS = 4096;                             // SBINS ints
    const size_t OFF_OVFCNT = OFF_COUNTS + (size_t)SBINS * 4;   // 1 int (in the memset span)
    const size_t OFF_OVF    = OFF_OVFCNT + 256;                 // OVF_MAX int2
    const size_t OFF_BUCKET = OFF_OVF + (size_t)OVF_MAX * 8;    // SBINS*CAP ints
    const size_t WS_NEEDED  = OFF_BUCKET + (size_t)SBINS * CAP * 4;

    prep_kernel<<<1, 64, 0, stream>>>(rots, trans, intrins, post_rots, post_trans, mats);

    if (ws_size >= WS_NEEDED) {
        int*  counts = (int*)((char*)d_ws + OFF_COUNTS);
        int*  ovfcnt = (int*)((char*)d_ws + OFF_OVFCNT);
        int2* ovf    = (int2*)((char*)d_ws + OFF_OVF);
        int*  bucket = (int*)((char*)d_ws + OFF_BUCKET);

        // one memset covers counts + ovfcnt
        hipMemsetAsync(counts, 0, (size_t)SBINS * 4 + 256, stream);

        const int ptBlocks = (NPTS + 255) / 256;  // 677
        bucket_kernel<<<ptBlocks, 256, 0, stream>>>(mats, counts, bucket, ovfcnt, ovf);

        dim3 ggrid(NXY / 32, BATCH);              // (1250, 4)
        gather3_kernel<<<ggrid, 256, 0, stream>>>(cam_feats, counts, bucket, ovfcnt, ovf, out);
    } else {
        hipMemsetAsync(d_out, 0, (size_t)out_size * sizeof(float), stream);
        scatter_direct_kernel<<<NPTS, CCH, 0, stream>>>(cam_feats, mats, out);
    }
}